// Round 10
// baseline (94.968 us; speedup 1.0000x reference)
//
#include <hip/hip_runtime.h>
#include <math.h>

// OneClassLoss: BS=128, HW=128. x1,x2: (128,1,128,128) fp32. Output: scalar fp32.
//
// ws layout (floats) — every region fully overwritten each launch (poison-proof):
//   [256,512)           Se[g]  = sum_j exp(D[g-half-row] - Mx[g])   (finish)
//   [512,768)           Mx[g]  = local max of D over half-row g     (finish)
//   [768,896)           Dii[i] = D[i][i]                            (finish)
//   [16640,18688)       NP[img*8+wave] norm partials                (main fft)
//   [20736,4215040)     Gp4[e16*1024+ks*4+q] interleaved Gram partials (main)
//   [4215040,6344960)   P[bin16*4096+img*16+m] interleaved PSD partials (main)
//   [6344960,6345025)   PS[k];  [6345025,6345090) PL[k]             (finish)

#define WS_SE    256
#define WS_MX    512
#define WS_DII   768
#define WS_NP    16640
#define WS_GP    20736
#define WS_P     4215040
#define WS_PS    6344960
#define WS_PL    6345025

#define PI_F 3.14159265358979323846f

// ---------------- Register/shuffle 128-pt complex FFT (DIF, bit-reversed out) --
__device__ __forceinline__ void fft128_reg(float& s0r, float& s0i,
                                           float& s1r, float& s1i,
                                           float cA, float sA,
                                           const float* wr, const float* wi,
                                           int lane) {
    float er = s0r + s1r, ei = s0i + s1i;
    float dr = s0r - s1r, di = s0i - s1i;
    float orr = dr * cA - di * sA;
    float oii = dr * sA + di * cA;
    #pragma unroll
    for (int st = 0; st < 6; ++st) {
        int m = 32 >> st;
        bool up = (lane & m) == 0;
        float tr = __shfl_xor(er, m), ti = __shfl_xor(ei, m);
        float ar = tr - er, ai = ti - ei;
        float e2r = up ? (er + tr) : (ar * wr[st] - ai * wi[st]);
        float e2i = up ? (ei + ti) : (ar * wi[st] + ai * wr[st]);
        tr = __shfl_xor(orr, m); ti = __shfl_xor(oii, m);
        float br_ = tr - orr, bi_ = ti - oii;
        float o2r = up ? (orr + tr) : (br_ * wr[st] - bi_ * wi[st]);
        float o2i = up ? (oii + ti) : (br_ * wi[st] + bi_ * wr[st]);
        er = e2r; ei = e2i; orr = o2r; oii = o2i;
    }
    s0r = er; s0i = ei; s1r = orr; s1i = oii;
}

// ---------------- Kernel 1: merged gram (blocks 0..255) + fft (256..511) -------
// __launch_bounds__(512,4): cap VGPR at 128 so 2 blocks/CU (gram+fft pairing).
__global__ __launch_bounds__(512, 4) void ocl_main(const float* __restrict__ x1,
                                                   const float* __restrict__ x2,
                                                   float* __restrict__ ws) {
    __shared__ float4 smem4[4096];     // 64 KB union
    int t = threadIdx.x;
    int bid = blockIdx.x;

    if (bid < 256) {
        // ================= GRAM K-split ks (K-chunk 64) =================
        // All 512 threads stage; 256 threads compute 8x8 tiles (better
        // LDS-reuse ratio: 1.05 MB vs 1.57 MB of ds_read_b128 per block).
        float4* As = smem4;            // [128][16] float4, XOR-swizzled
        float4* Bs = smem4 + 2048;
        int ks = bid, k0q = ks * 16;
        const float4* A = (const float4*)x1;
        const float4* B = (const float4*)x2;
        {
            int qi = t & 15, r0 = t >> 4;
            #pragma unroll
            for (int p = 0; p < 4; ++p) {
                int r = r0 + 32 * p;
                int sq = qi ^ ((r >> 3) & 7);
                As[r * 16 + sq] = A[(size_t)r * 4096 + k0q + qi];
                Bs[r * 16 + sq] = B[(size_t)r * 4096 + k0q + qi];
            }
        }
        __syncthreads();
        if (t >= 256) return;          // 4 waves retire; no further barriers

        int ty = t >> 4, tx = t & 15;  // rows ty*8.., cols tx*8..
        float acc[8][8];
        #pragma unroll
        for (int r = 0; r < 8; ++r)
            #pragma unroll
            for (int c = 0; c < 8; ++c) acc[r][c] = 0.0f;

        for (int qk = 0; qk < 16; ++qk) {
            int sa = qk ^ (ty & 7);    // (row>>3)&7 == ty for rows ty*8..+8
            int sb = qk ^ (tx & 7);
            float4 a4[8];
            #pragma unroll
            for (int r = 0; r < 8; ++r) a4[r] = As[(ty * 8 + r) * 16 + sa];
            // B in two halves of 4 to keep VGPR under 128
            #pragma unroll
            for (int h = 0; h < 2; ++h) {
                float4 b4[4];
                #pragma unroll
                for (int c = 0; c < 4; ++c)
                    b4[c] = Bs[(tx * 8 + h * 4 + c) * 16 + sb];
                #pragma unroll
                for (int r = 0; r < 8; ++r)
                    #pragma unroll
                    for (int c = 0; c < 4; ++c) {
                        float4 a = a4[r], b = b4[c];
                        acc[r][h * 4 + c] = fmaf(a.x, b.x, fmaf(a.y, b.y,
                            fmaf(a.z, b.z, fmaf(a.w, b.w, acc[r][h * 4 + c]))));
                    }
            }
        }

        // Interleaved store: Gp4[e4>>2][ks*4 + (e4&3)], e4 = row*32 + colquad
        float4* Gp4 = (float4*)(ws + WS_GP);
        #pragma unroll
        for (int r = 0; r < 8; ++r)
            #pragma unroll
            for (int cc = 0; cc < 2; ++cc) {
                int e4 = (ty * 8 + r) * 32 + tx * 2 + cc;
                Gp4[(size_t)(e4 >> 2) * 1024 + ks * 4 + (e4 & 3)] =
                    make_float4(acc[r][cc * 4 + 0], acc[r][cc * 4 + 1],
                                acc[r][cc * 4 + 2], acc[r][cc * 4 + 3]);
            }
    } else {
        // ================= FFT + PSD + norm partials (no atomics) =======
        float* zre = (float*)smem4;
        float* zim = zre + 8192;
        int lane = t & 63, wave = t >> 6;   // 8 waves
        int img = bid - 256;
        const float* src = (img < 128) ? (x1 + (size_t)img * 16384)
                                       : (x2 + (size_t)(img - 128) * 16384);

        float cA, sA, wr[6], wi[6];
        {
            float th = -PI_F * (float)lane / 64.0f;
            sA = __sinf(th); cA = __cosf(th);
            #pragma unroll
            for (int st = 0; st < 6; ++st) {
                int m = 32 >> st;
                float a = -PI_F * (float)(lane & (m - 1)) / (float)m;
                wi[st] = __sinf(a); wr[st] = __cosf(a);
            }
        }
        int rb = (int)(__brev((unsigned)lane) >> 26);  // br6(lane)

        float nrm = 0.0f;
        #pragma unroll
        for (int pi = 0; pi < 8; ++pi) {
            int p = wave * 8 + pi;
            const float* r0 = src + p * 256 + lane;
            float s0r = r0[0],   s1r = r0[64];
            float s0i = r0[128], s1i = r0[192];
            nrm += s0r * s0r + s1r * s1r + s0i * s0i + s1i * s1i;
            fft128_reg(s0r, s0i, s1r, s1i, cA, sA, wr, wi, lane);
            int f0 = (2 * rb + p) & 127;
            int f1 = (2 * rb + 1 + p) & 127;
            zre[p * 128 + f0] = s0r; zim[p * 128 + f0] = s0i;
            zre[p * 128 + f1] = s1r; zim[p * 128 + f1] = s1i;
        }
        for (int off = 32; off >= 1; off >>= 1) nrm += __shfl_xor(nrm, off);
        if (lane == 0) ws[WS_NP + img * 8 + wave] = nrm;   // plain store
        __syncthreads();

        int p0 = (lane >> 1), p1 = 32 + (lane >> 1);
        int par = lane & 1;
        float* P = ws + WS_P;
        for (int k = wave; k < 65; k += 8) {
            float v0r, v0i, v1r, v1i;
            if (k == 0 || k == 64) {
                int c0 = (k + p0) & 127, c1 = (k + p1) & 127;
                float Z0r = zre[p0 * 128 + c0], Z0i = zim[p0 * 128 + c0];
                float Z1r = zre[p1 * 128 + c1], Z1i = zim[p1 * 128 + c1];
                v0r = par ? Z0i : Z0r; v0i = 0.0f;
                v1r = par ? Z1i : Z1r; v1i = 0.0f;
            } else {
                int kn = 128 - k;
                int ck = (k + p0) & 127, cn = (kn + p0) & 127;
                float Zkr = zre[p0 * 128 + ck], Zki = zim[p0 * 128 + ck];
                float Znr = zre[p0 * 128 + cn], Zni = zim[p0 * 128 + cn];
                float e0r = 0.5f * (Zkr + Znr), e0i = 0.5f * (Zki - Zni);
                float q0r = 0.5f * (Zki + Zni), q0i = 0.5f * (Znr - Zkr);
                v0r = par ? q0r : e0r; v0i = par ? q0i : e0i;
                ck = (k + p1) & 127; cn = (kn + p1) & 127;
                Zkr = zre[p1 * 128 + ck]; Zki = zim[p1 * 128 + ck];
                Znr = zre[p1 * 128 + cn]; Zni = zim[p1 * 128 + cn];
                float e1r = 0.5f * (Zkr + Znr), e1i = 0.5f * (Zki - Zni);
                float q1r = 0.5f * (Zki + Zni), q1i = 0.5f * (Znr - Zkr);
                v1r = par ? q1r : e1r; v1i = par ? q1i : e1i;
            }
            fft128_reg(v0r, v0i, v1r, v1i, cA, sA, wr, wi, lane);
            int m = lane & 15, hi = lane >> 4;
            P[(size_t)(k * 8 + 0 + hi) * 4096 + img * 16 + m] = v0r * v0r + v0i * v0i;
            P[(size_t)(k * 8 + 4 + hi) * 4096 + img * 16 + m] = v1r * v1r + v1i * v1i;
        }
    }
}

// ---------------- Kernel 2: reductions (grid 321) ------------------------------
// blocks [0,256): block g: Gp slice -> D half-row -> (Mx[g], Se[g], Dii)
// blocks [256,321): PSD bins of column k=bid-256 -> PS[k], PL[k]
__global__ __launch_bounds__(256) void ocl_finish(float* __restrict__ ws) {
    int bid = blockIdx.x, t = threadIdx.x;
    int lane = t & 63, wave = t >> 6;

    if (bid < 256) {
        int g = bid;
        const float4* Gp4 = (const float4*)(ws + WS_GP);
        int q = (lane >> 4) & 3, kg = lane & 15;
        const float4* base = Gp4 + (size_t)g * 4096 + wave * 1024 + q;
        float4 v[16];
        #pragma unroll
        for (int it = 0; it < 16; ++it) v[it] = base[(kg * 16 + it) * 4];

        // na/nb from NP partials (cooperative, LDS)
        __shared__ float nbs[64];
        __shared__ float s_na;
        __shared__ float sm[4], sm2[4];
        if (t < 64) {
            const float* np = ws + WS_NP + (size_t)(128 + (g & 1) * 64 + t) * 8;
            nbs[t] = ((np[0] + np[1]) + (np[2] + np[3])) +
                     ((np[4] + np[5]) + (np[6] + np[7]));
        }
        if (t == 64) {
            const float* np = ws + WS_NP + (size_t)(g >> 1) * 8;
            s_na = ((np[0] + np[1]) + (np[2] + np[3])) +
                   ((np[4] + np[5]) + (np[6] + np[7]));
        }

        float4 s = v[0];
        #pragma unroll
        for (int it = 1; it < 16; ++it) {
            s.x += v[it].x; s.y += v[it].y; s.z += v[it].z; s.w += v[it].w;
        }
        #pragma unroll
        for (int msk = 1; msk <= 8; msk <<= 1) {
            s.x += __shfl_xor(s.x, msk); s.y += __shfl_xor(s.y, msk);
            s.z += __shfl_xor(s.z, msk); s.w += __shfl_xor(s.w, msk);
        }
        __syncthreads();   // nbs / s_na ready

        int cq = wave * 4 + q;           // column quad 0..15 within half-row
        float nai = s_na;
        float4 d;
        d.x = sqrtf(fmaxf(nai + nbs[cq * 4 + 0] - 2.0f * s.x, 0.0f));
        d.y = sqrtf(fmaxf(nai + nbs[cq * 4 + 1] - 2.0f * s.y, 0.0f));
        d.z = sqrtf(fmaxf(nai + nbs[cq * 4 + 2] - 2.0f * s.z, 0.0f));
        d.w = sqrtf(fmaxf(nai + nbs[cq * 4 + 3] - 2.0f * s.w, 0.0f));

        // Diagonal
        int i = g >> 1;
        int jr = i - (g & 1) * 64;
        if (kg == 0 && jr >= 0 && jr < 64 && cq == (jr >> 2)) {
            float dii = (jr & 2) ? ((jr & 1) ? d.w : d.z) : ((jr & 1) ? d.y : d.x);
            ws[WS_DII + i] = dii;
        }

        // Local max over the half-row
        float m = fmaxf(fmaxf(d.x, d.y), fmaxf(d.z, d.w));
        m = fmaxf(m, __shfl_xor(m, 16));
        m = fmaxf(m, __shfl_xor(m, 32));
        if (lane == 0) sm[wave] = m;
        __syncthreads();
        float M = fmaxf(fmaxf(sm[0], sm[1]), fmaxf(sm[2], sm[3]));

        // Sum of exp(d - M)
        float se = __expf(d.x - M) + __expf(d.y - M) +
                   __expf(d.z - M) + __expf(d.w - M);
        se += __shfl_xor(se, 16);
        se += __shfl_xor(se, 32);
        if (lane == 0) sm2[wave] = se;
        __syncthreads();
        if (t == 0) {
            ws[WS_SE + g] = sm2[0] + sm2[1] + sm2[2] + sm2[3];
            ws[WS_MX + g] = M;
        }
    } else {
        int k = bid - 256;
        const float4* P4 = (const float4*)(ws + WS_P);
        int b16 = t >> 5, m4 = (t >> 3) & 3, hq = t & 7;
        const float4* base = P4 + (size_t)(k * 8 + b16) * 1024 + m4;
        float4 s = make_float4(0.f, 0.f, 0.f, 0.f);
        #pragma unroll
        for (int half = 0; half < 2; ++half) {
            float4 u[16];
            #pragma unroll
            for (int it = 0; it < 16; ++it)
                u[it] = base[(hq * 32 + half * 16 + it) * 4];
            #pragma unroll
            for (int it = 0; it < 16; ++it) {
                s.x += u[it].x; s.y += u[it].y; s.z += u[it].z; s.w += u[it].w;
            }
        }
        #pragma unroll
        for (int msk = 1; msk <= 4; msk <<= 1) {
            s.x += __shfl_xor(s.x, msk); s.y += __shfl_xor(s.y, msk);
            s.z += __shfl_xor(s.z, msk); s.w += __shfl_xor(s.w, msk);
        }
        float sS = 0.0f, sL = 0.0f;
        if (hq == 0) {
            float w = (k == 0 || k == 64) ? 1.0f : 2.0f;
            sS = w * (s.x + s.y + s.z + s.w);
            sL = w * (logf(s.x) + logf(s.y) + logf(s.z) + logf(s.w));
        }
        #pragma unroll
        for (int off = 32; off >= 1; off >>= 1) {
            sS += __shfl_xor(sS, off);
            sL += __shfl_xor(sL, off);
        }
        __shared__ float aS[4], aL[4];
        if (lane == 0) { aS[wave] = sS; aL[wave] = sL; }
        __syncthreads();
        if (t == 0) {
            ws[WS_PS + k] = aS[0] + aS[1] + aS[2] + aS[3];
            ws[WS_PL + k] = aL[0] + aL[1] + aL[2] + aL[3];
        }
    }
}

// ---------------- Kernel 3: tail — merge half-row LSE partials + PSD -> scalar -
__global__ __launch_bounds__(256) void ocl_tail(const float* __restrict__ ws,
                                                float* __restrict__ out) {
    int t = threadIdx.x, lane = t & 63, wave = t >> 6;

    float rowacc = 0.0f;
    if (t < 128) {
        int i = t;
        float sea = ws[WS_SE + 2 * i],     seb = ws[WS_SE + 2 * i + 1];
        float ma  = ws[WS_MX + 2 * i],     mb  = ws[WS_MX + 2 * i + 1];
        float dii = ws[WS_DII + i];
        float M = fmaxf(ma, mb);
        float se = sea * __expf(ma - M) + seb * __expf(mb - M);
        rowacc = M + logf(se) - dii;
    }

    float sS = 0.0f, sL = 0.0f;
    if (t < 65) { sS = ws[WS_PS + t]; sL = ws[WS_PL + t]; }
    #pragma unroll
    for (int off = 32; off >= 1; off >>= 1) {
        sS += __shfl_xor(sS, off);
        sL += __shfl_xor(sL, off);
        rowacc += __shfl_xor(rowacc, off);
    }
    __shared__ float bS[4], bL[4], bR[4];
    if (lane == 0) { bS[wave] = sS; bL[wave] = sL; bR[wave] = rowacc; }
    __syncthreads();
    if (t == 0) {
        float S_ = bS[0] + bS[1] + bS[2] + bS[3];
        float L_ = bL[0] + bL[1] + bL[2] + bL[3];
        float R_ = bR[0] + bR[1] + bR[2] + bR[3];
        float ce = R_ / 128.0f;
        float r  = L_ / 16384.0f - logf(S_ / 16384.0f);
        out[0] = ce - 0.1f * r;
    }
}

extern "C" void kernel_launch(void* const* d_in, const int* in_sizes, int n_in,
                              void* d_out, int out_size, void* d_ws, size_t ws_size,
                              hipStream_t stream) {
    (void)in_sizes; (void)n_in; (void)out_size; (void)ws_size;
    const float* x1 = (const float*)d_in[0];
    const float* x2 = (const float*)d_in[1];
    float* ws  = (float*)d_ws;
    float* out = (float*)d_out;

    hipLaunchKernelGGL(ocl_main,   dim3(512), dim3(512), 0, stream, x1, x2, ws);
    hipLaunchKernelGGL(ocl_finish, dim3(321), dim3(256), 0, stream, ws);
    hipLaunchKernelGGL(ocl_tail,   dim3(1),   dim3(256), 0, stream, ws, out);
}

// Round 11
// 91.769 us; speedup vs baseline: 1.0349x; 1.0349x over previous
//
#include <hip/hip_runtime.h>
#include <math.h>

// OneClassLoss: BS=128, HW=128. x1,x2: (128,1,128,128) fp32. Output: scalar fp32.
//
// ws layout (floats) — every region fully overwritten each launch (poison-proof):
//   [256,512)           Se[g]  = sum_j exp(D[g-half-row] - Mx[g])   (finish)
//   [512,768)           Mx[g]  = local max of D over half-row g     (finish)
//   [768,896)           Dii[i] = D[i][i]                            (finish)
//   [16640,18688)       NP[img*8+wave] norm partials                (main fft)
//   [20736,4215040)     Gp4[e16*1024+ks*4+q] interleaved Gram partials (main)
//   [4215040,6344960)   P[bin16*4096+img*16+m] interleaved PSD partials (main)
//   [6344960,6345025)   PS[k];  [6345025,6345090) PL[k]             (finish)

#define WS_SE    256
#define WS_MX    512
#define WS_DII   768
#define WS_NP    16640
#define WS_GP    20736
#define WS_P     4215040
#define WS_PS    6344960
#define WS_PL    6345025

#define PI_F 3.14159265358979323846f

// Cross-lane exchange helpers. xor1/xor2 via DPP quad_perm run on the VALU
// pipe (free of the contended per-CU DS pipe); xor4..32 stay ds_swizzle/permute.
#define SHX32(v) __shfl_xor((v), 32)
#define SHX16(v) __shfl_xor((v), 16)
#define SHX8(v)  __shfl_xor((v), 8)
#define SHX4(v)  __shfl_xor((v), 4)
__device__ __forceinline__ float DPPX2(float v) {   // lane ^ 2: quad_perm [2,3,0,1]
    return __int_as_float(__builtin_amdgcn_mov_dpp(__float_as_int(v), 0x4E, 0xf, 0xf, true));
}
__device__ __forceinline__ float DPPX1(float v) {   // lane ^ 1: quad_perm [1,0,3,2]
    return __int_as_float(__builtin_amdgcn_mov_dpp(__float_as_int(v), 0xB1, 0xf, 0xf, true));
}

// ---------------- Register/shuffle 128-pt complex FFT (DIF, bit-reversed out) --
__device__ __forceinline__ void fft128_reg(float& s0r, float& s0i,
                                           float& s1r, float& s1i,
                                           float cA, float sA,
                                           const float* wr, const float* wi,
                                           int lane) {
    float er = s0r + s1r, ei = s0i + s1i;
    float dr = s0r - s1r, di = s0i - s1i;
    float orr = dr * cA - di * sA;
    float oii = dr * sA + di * cA;
#define OCL_ST(ST, M, EXCH)                                           \
    { bool up = (lane & (M)) == 0;                                    \
      float tr = EXCH(er), ti = EXCH(ei);                             \
      float ar = tr - er, ai = ti - ei;                               \
      float e2r = up ? (er + tr) : (ar * wr[ST] - ai * wi[ST]);       \
      float e2i = up ? (ei + ti) : (ar * wi[ST] + ai * wr[ST]);       \
      tr = EXCH(orr); ti = EXCH(oii);                                 \
      float br_ = tr - orr, bi_ = ti - oii;                           \
      float o2r = up ? (orr + tr) : (br_ * wr[ST] - bi_ * wi[ST]);    \
      float o2i = up ? (oii + ti) : (br_ * wi[ST] + bi_ * wr[ST]);    \
      er = e2r; ei = e2i; orr = o2r; oii = o2i; }
    OCL_ST(0, 32, SHX32)
    OCL_ST(1, 16, SHX16)
    OCL_ST(2, 8,  SHX8)
    OCL_ST(3, 4,  SHX4)
    OCL_ST(4, 2,  DPPX2)
    OCL_ST(5, 1,  DPPX1)
#undef OCL_ST
    s0r = er; s0i = ei; s1r = orr; s1i = oii;
}

// ---------------- Kernel 1: merged gram (blocks 0..255) + fft (256..511) -------
// __launch_bounds__(512,4): cap VGPR at 128 so 2 blocks/CU (gram+fft pairing).
__global__ __launch_bounds__(512, 4) void ocl_main(const float* __restrict__ x1,
                                                   const float* __restrict__ x2,
                                                   float* __restrict__ ws) {
    __shared__ float4 smem4[4096];     // 64 KB union (gram uses half; fft all)
    int t = threadIdx.x;
    int bid = blockIdx.x;

    if (bid < 256) {
        // ================= GRAM K-split ks (K-chunk 64) =================
        // B staged in LDS (XOR-swizzled); A read straight from global with
        // 16-lane-uniform addresses (broadcast loads, TA pipe) — halves the
        // block's DS-pipe traffic vs staging both.
        float4* Bs = smem4;            // [128][16] float4, XOR-swizzled
        int ks = bid, k0q = ks * 16;
        const float4* A = (const float4*)x1;
        const float4* B = (const float4*)x2;
        {
            int qi = t & 15, r0 = t >> 4;
            #pragma unroll
            for (int p = 0; p < 4; ++p) {
                int r = r0 + 32 * p;
                int sq = qi ^ ((r >> 3) & 7);
                Bs[r * 16 + sq] = B[(size_t)r * 4096 + k0q + qi];
            }
        }
        __syncthreads();
        if (t >= 256) return;          // 4 waves retire; no further barriers

        int ty = t >> 4, tx = t & 15;  // rows ty*8.., cols tx*8..
        const float4* Arow = A + (size_t)(ty * 8) * 4096 + k0q;
        float acc[8][8];
        #pragma unroll
        for (int r = 0; r < 8; ++r)
            #pragma unroll
            for (int c = 0; c < 8; ++c) acc[r][c] = 0.0f;

        for (int qk = 0; qk < 16; ++qk) {
            int sb = qk ^ (tx & 7);
            float4 b4[8];
            #pragma unroll
            for (int c = 0; c < 8; ++c)
                b4[c] = Bs[(tx * 8 + c) * 16 + sb];
            #pragma unroll
            for (int rh = 0; rh < 2; ++rh) {
                float4 a4[4];
                #pragma unroll
                for (int r = 0; r < 4; ++r)
                    a4[r] = Arow[(size_t)(rh * 4 + r) * 4096 + qk];
                #pragma unroll
                for (int r = 0; r < 4; ++r)
                    #pragma unroll
                    for (int c = 0; c < 8; ++c) {
                        float4 a = a4[r], b = b4[c];
                        acc[rh * 4 + r][c] = fmaf(a.x, b.x, fmaf(a.y, b.y,
                            fmaf(a.z, b.z, fmaf(a.w, b.w, acc[rh * 4 + r][c]))));
                    }
            }
        }

        // Interleaved store: Gp4[e4>>2][ks*4 + (e4&3)], e4 = row*32 + colquad
        float4* Gp4 = (float4*)(ws + WS_GP);
        #pragma unroll
        for (int r = 0; r < 8; ++r)
            #pragma unroll
            for (int cc = 0; cc < 2; ++cc) {
                int e4 = (ty * 8 + r) * 32 + tx * 2 + cc;
                Gp4[(size_t)(e4 >> 2) * 1024 + ks * 4 + (e4 & 3)] =
                    make_float4(acc[r][cc * 4 + 0], acc[r][cc * 4 + 1],
                                acc[r][cc * 4 + 2], acc[r][cc * 4 + 3]);
            }
    } else {
        // ================= FFT + PSD + norm partials (no atomics) =======
        float* zre = (float*)smem4;
        float* zim = zre + 8192;
        int lane = t & 63, wave = t >> 6;   // 8 waves
        int img = bid - 256;
        const float* src = (img < 128) ? (x1 + (size_t)img * 16384)
                                       : (x2 + (size_t)(img - 128) * 16384);

        float cA, sA, wr[6], wi[6];
        {
            float th = -PI_F * (float)lane / 64.0f;
            sA = __sinf(th); cA = __cosf(th);
            #pragma unroll
            for (int st = 0; st < 6; ++st) {
                int m = 32 >> st;
                float a = -PI_F * (float)(lane & (m - 1)) / (float)m;
                wi[st] = __sinf(a); wr[st] = __cosf(a);
            }
        }
        int rb = (int)(__brev((unsigned)lane) >> 26);  // br6(lane)

        float nrm = 0.0f;
        #pragma unroll
        for (int pi = 0; pi < 8; ++pi) {
            int p = wave * 8 + pi;
            const float* r0 = src + p * 256 + lane;
            float s0r = r0[0],   s1r = r0[64];
            float s0i = r0[128], s1i = r0[192];
            nrm += s0r * s0r + s1r * s1r + s0i * s0i + s1i * s1i;
            fft128_reg(s0r, s0i, s1r, s1i, cA, sA, wr, wi, lane);
            int f0 = (2 * rb + p) & 127;
            int f1 = (2 * rb + 1 + p) & 127;
            zre[p * 128 + f0] = s0r; zim[p * 128 + f0] = s0i;
            zre[p * 128 + f1] = s1r; zim[p * 128 + f1] = s1i;
        }
        for (int off = 32; off >= 1; off >>= 1) nrm += __shfl_xor(nrm, off);
        if (lane == 0) ws[WS_NP + img * 8 + wave] = nrm;   // plain store
        __syncthreads();

        int p0 = (lane >> 1), p1 = 32 + (lane >> 1);
        int par = lane & 1;
        float* P = ws + WS_P;
        for (int k = wave; k < 65; k += 8) {
            float v0r, v0i, v1r, v1i;
            if (k == 0 || k == 64) {
                int c0 = (k + p0) & 127, c1 = (k + p1) & 127;
                float Z0r = zre[p0 * 128 + c0], Z0i = zim[p0 * 128 + c0];
                float Z1r = zre[p1 * 128 + c1], Z1i = zim[p1 * 128 + c1];
                v0r = par ? Z0i : Z0r; v0i = 0.0f;
                v1r = par ? Z1i : Z1r; v1i = 0.0f;
            } else {
                int kn = 128 - k;
                int ck = (k + p0) & 127, cn = (kn + p0) & 127;
                float Zkr = zre[p0 * 128 + ck], Zki = zim[p0 * 128 + ck];
                float Znr = zre[p0 * 128 + cn], Zni = zim[p0 * 128 + cn];
                float e0r = 0.5f * (Zkr + Znr), e0i = 0.5f * (Zki - Zni);
                float q0r = 0.5f * (Zki + Zni), q0i = 0.5f * (Znr - Zkr);
                v0r = par ? q0r : e0r; v0i = par ? q0i : e0i;
                ck = (k + p1) & 127; cn = (kn + p1) & 127;
                Zkr = zre[p1 * 128 + ck]; Zki = zim[p1 * 128 + ck];
                Znr = zre[p1 * 128 + cn]; Zni = zim[p1 * 128 + cn];
                float e1r = 0.5f * (Zkr + Znr), e1i = 0.5f * (Zki - Zni);
                float q1r = 0.5f * (Zki + Zni), q1i = 0.5f * (Znr - Zkr);
                v1r = par ? q1r : e1r; v1i = par ? q1i : e1i;
            }
            fft128_reg(v0r, v0i, v1r, v1i, cA, sA, wr, wi, lane);
            int m = lane & 15, hi = lane >> 4;
            P[(size_t)(k * 8 + 0 + hi) * 4096 + img * 16 + m] = v0r * v0r + v0i * v0i;
            P[(size_t)(k * 8 + 4 + hi) * 4096 + img * 16 + m] = v1r * v1r + v1i * v1i;
        }
    }
}

// ---------------- Kernel 2: reductions (grid 321) ------------------------------
// blocks [0,256): block g: Gp slice -> D half-row -> (Mx[g], Se[g], Dii)
// blocks [256,321): PSD bins of column k=bid-256 -> PS[k], PL[k]
__global__ __launch_bounds__(256) void ocl_finish(float* __restrict__ ws) {
    int bid = blockIdx.x, t = threadIdx.x;
    int lane = t & 63, wave = t >> 6;

    if (bid < 256) {
        int g = bid;
        const float4* Gp4 = (const float4*)(ws + WS_GP);
        int q = (lane >> 4) & 3, kg = lane & 15;
        const float4* base = Gp4 + (size_t)g * 4096 + wave * 1024 + q;
        float4 v[16];
        #pragma unroll
        for (int it = 0; it < 16; ++it) v[it] = base[(kg * 16 + it) * 4];

        // na/nb from NP partials (cooperative, LDS)
        __shared__ float nbs[64];
        __shared__ float s_na;
        __shared__ float sm[4], sm2[4];
        if (t < 64) {
            const float* np = ws + WS_NP + (size_t)(128 + (g & 1) * 64 + t) * 8;
            nbs[t] = ((np[0] + np[1]) + (np[2] + np[3])) +
                     ((np[4] + np[5]) + (np[6] + np[7]));
        }
        if (t == 64) {
            const float* np = ws + WS_NP + (size_t)(g >> 1) * 8;
            s_na = ((np[0] + np[1]) + (np[2] + np[3])) +
                   ((np[4] + np[5]) + (np[6] + np[7]));
        }

        float4 s = v[0];
        #pragma unroll
        for (int it = 1; it < 16; ++it) {
            s.x += v[it].x; s.y += v[it].y; s.z += v[it].z; s.w += v[it].w;
        }
        #pragma unroll
        for (int msk = 1; msk <= 8; msk <<= 1) {
            s.x += __shfl_xor(s.x, msk); s.y += __shfl_xor(s.y, msk);
            s.z += __shfl_xor(s.z, msk); s.w += __shfl_xor(s.w, msk);
        }
        __syncthreads();   // nbs / s_na ready

        int cq = wave * 4 + q;           // column quad 0..15 within half-row
        float nai = s_na;
        float4 d;
        d.x = sqrtf(fmaxf(nai + nbs[cq * 4 + 0] - 2.0f * s.x, 0.0f));
        d.y = sqrtf(fmaxf(nai + nbs[cq * 4 + 1] - 2.0f * s.y, 0.0f));
        d.z = sqrtf(fmaxf(nai + nbs[cq * 4 + 2] - 2.0f * s.z, 0.0f));
        d.w = sqrtf(fmaxf(nai + nbs[cq * 4 + 3] - 2.0f * s.w, 0.0f));

        // Diagonal
        int i = g >> 1;
        int jr = i - (g & 1) * 64;
        if (kg == 0 && jr >= 0 && jr < 64 && cq == (jr >> 2)) {
            float dii = (jr & 2) ? ((jr & 1) ? d.w : d.z) : ((jr & 1) ? d.y : d.x);
            ws[WS_DII + i] = dii;
        }

        // Local max over the half-row
        float m = fmaxf(fmaxf(d.x, d.y), fmaxf(d.z, d.w));
        m = fmaxf(m, __shfl_xor(m, 16));
        m = fmaxf(m, __shfl_xor(m, 32));
        if (lane == 0) sm[wave] = m;
        __syncthreads();
        float M = fmaxf(fmaxf(sm[0], sm[1]), fmaxf(sm[2], sm[3]));

        // Sum of exp(d - M)
        float se = __expf(d.x - M) + __expf(d.y - M) +
                   __expf(d.z - M) + __expf(d.w - M);
        se += __shfl_xor(se, 16);
        se += __shfl_xor(se, 32);
        if (lane == 0) sm2[wave] = se;
        __syncthreads();
        if (t == 0) {
            ws[WS_SE + g] = sm2[0] + sm2[1] + sm2[2] + sm2[3];
            ws[WS_MX + g] = M;
        }
    } else {
        int k = bid - 256;
        const float4* P4 = (const float4*)(ws + WS_P);
        int b16 = t >> 5, m4 = (t >> 3) & 3, hq = t & 7;
        const float4* base = P4 + (size_t)(k * 8 + b16) * 1024 + m4;
        float4 s = make_float4(0.f, 0.f, 0.f, 0.f);
        #pragma unroll
        for (int half = 0; half < 2; ++half) {
            float4 u[16];
            #pragma unroll
            for (int it = 0; it < 16; ++it)
                u[it] = base[(hq * 32 + half * 16 + it) * 4];
            #pragma unroll
            for (int it = 0; it < 16; ++it) {
                s.x += u[it].x; s.y += u[it].y; s.z += u[it].z; s.w += u[it].w;
            }
        }
        #pragma unroll
        for (int msk = 1; msk <= 4; msk <<= 1) {
            s.x += __shfl_xor(s.x, msk); s.y += __shfl_xor(s.y, msk);
            s.z += __shfl_xor(s.z, msk); s.w += __shfl_xor(s.w, msk);
        }
        float sS = 0.0f, sL = 0.0f;
        if (hq == 0) {
            float w = (k == 0 || k == 64) ? 1.0f : 2.0f;
            sS = w * (s.x + s.y + s.z + s.w);
            sL = w * (logf(s.x) + logf(s.y) + logf(s.z) + logf(s.w));
        }
        #pragma unroll
        for (int off = 32; off >= 1; off >>= 1) {
            sS += __shfl_xor(sS, off);
            sL += __shfl_xor(sL, off);
        }
        __shared__ float aS[4], aL[4];
        if (lane == 0) { aS[wave] = sS; aL[wave] = sL; }
        __syncthreads();
        if (t == 0) {
            ws[WS_PS + k] = aS[0] + aS[1] + aS[2] + aS[3];
            ws[WS_PL + k] = aL[0] + aL[1] + aL[2] + aL[3];
        }
    }
}

// ---------------- Kernel 3: tail — merge half-row LSE partials + PSD -> scalar -
__global__ __launch_bounds__(256) void ocl_tail(const float* __restrict__ ws,
                                                float* __restrict__ out) {
    int t = threadIdx.x, lane = t & 63, wave = t >> 6;

    float rowacc = 0.0f;
    if (t < 128) {
        int i = t;
        float sea = ws[WS_SE + 2 * i],     seb = ws[WS_SE + 2 * i + 1];
        float ma  = ws[WS_MX + 2 * i],     mb  = ws[WS_MX + 2 * i + 1];
        float dii = ws[WS_DII + i];
        float M = fmaxf(ma, mb);
        float se = sea * __expf(ma - M) + seb * __expf(mb - M);
        rowacc = M + logf(se) - dii;
    }

    float sS = 0.0f, sL = 0.0f;
    if (t < 65) { sS = ws[WS_PS + t]; sL = ws[WS_PL + t]; }
    #pragma unroll
    for (int off = 32; off >= 1; off >>= 1) {
        sS += __shfl_xor(sS, off);
        sL += __shfl_xor(sL, off);
        rowacc += __shfl_xor(rowacc, off);
    }
    __shared__ float bS[4], bL[4], bR[4];
    if (lane == 0) { bS[wave] = sS; bL[wave] = sL; bR[wave] = rowacc; }
    __syncthreads();
    if (t == 0) {
        float S_ = bS[0] + bS[1] + bS[2] + bS[3];
        float L_ = bL[0] + bL[1] + bL[2] + bL[3];
        float R_ = bR[0] + bR[1] + bR[2] + bR[3];
        float ce = R_ / 128.0f;
        float r  = L_ / 16384.0f - logf(S_ / 16384.0f);
        out[0] = ce - 0.1f * r;
    }
}

extern "C" void kernel_launch(void* const* d_in, const int* in_sizes, int n_in,
                              void* d_out, int out_size, void* d_ws, size_t ws_size,
                              hipStream_t stream) {
    (void)in_sizes; (void)n_in; (void)out_size; (void)ws_size;
    const float* x1 = (const float*)d_in[0];
    const float* x2 = (const float*)d_in[1];
    float* ws  = (float*)d_ws;
    float* out = (float*)d_out;

    hipLaunchKernelGGL(ocl_main,   dim3(512), dim3(512), 0, stream, x1, x2, ws);
    hipLaunchKernelGGL(ocl_finish, dim3(321), dim3(256), 0, stream, ws);
    hipLaunchKernelGGL(ocl_tail,   dim3(1),   dim3(256), 0, stream, ws, out);
}